// Round 3
// baseline (1683.958 us; speedup 1.0000x reference)
//
#include <hip/hip_runtime.h>
#include <hip/hip_bf16.h>

#define Bb 64
#define Ss 20
#define Hh 128
#define Vv 50257
#define Ee 300
#define Vpad 50304   // 393*128

typedef short bf16x8 __attribute__((ext_vector_type(8)));
typedef float f32x4 __attribute__((ext_vector_type(4)));

__device__ __forceinline__ unsigned short f2bf(float f){
  unsigned u = __float_as_uint(f);
  u += 0x7fff + ((u >> 16) & 1);      // round-to-nearest-even
  return (unsigned short)(u >> 16);
}
__device__ __forceinline__ float blo(unsigned u){ return __uint_as_float(u << 16); }
__device__ __forceinline__ float bhi(unsigned u){ return __uint_as_float(u & 0xffff0000u); }
__device__ __forceinline__ float sigm(float x){ return 1.f / (1.f + __expf(-x)); }
__device__ __forceinline__ float tanh_fast(float x){
  float e = __expf(2.f * x);
  return 1.f - 2.f / (e + 1.f);
}

// Packed-bf16 GEMV dot: wp layout [K8][O] of uint4 (8 bf16 along K, lane=o coalesced).
// x: fp32 in LDS, 16B-aligned.
template<int K8, int O>
__device__ __forceinline__ float dotP(const uint4* __restrict__ wp, int o, const float* x){
  float a0=0.f, a1=0.f, a2=0.f, a3=0.f;
  const float4* x4 = (const float4*)x;
#pragma unroll
  for (int kk = 0; kk < K8; kk++){
    uint4 u = wp[kk*O + o];
    float4 xa = x4[2*kk], xb = x4[2*kk+1];
    a0 = fmaf(blo(u.x), xa.x, a0); a1 = fmaf(bhi(u.x), xa.y, a1);
    a2 = fmaf(blo(u.y), xa.z, a2); a3 = fmaf(bhi(u.y), xa.w, a3);
    a0 = fmaf(blo(u.z), xb.x, a0); a1 = fmaf(bhi(u.z), xb.y, a1);
    a2 = fmaf(blo(u.w), xb.z, a2); a3 = fmaf(bhi(u.w), xb.w, a3);
  }
  return (a0 + a1) + (a2 + a3);
}

// ---------------- weight pack: fp32 [Ktot][O] row-slice -> bf16 uint4 [K8][O] ----------------

struct PD { const float* src; uint4* dst; int r0, K, O; };
struct PL { PD m[15]; };

__global__ __launch_bounds__(256) void pack_kernel(PL L){
  PD p = L.m[blockIdx.y];
  int K8 = (p.K + 7) >> 3;
  int idx = blockIdx.x * 256 + threadIdx.x;
  if (idx >= K8 * p.O) return;
  int kk = idx / p.O, o = idx - kk * p.O;
  unsigned w[8];
#pragma unroll
  for (int j = 0; j < 8; j++){
    int k = 8*kk + j;
    float f = (k < p.K) ? p.src[(size_t)(p.r0 + k) * p.O + o] : 0.f;
    w[j] = f2bf(f);
  }
  uint4 u;
  u.x = w[0] | (w[1] << 16);
  u.y = w[2] | (w[3] << 16);
  u.z = w[4] | (w[5] << 16);
  u.w = w[6] | (w[7] << 16);
  p.dst[idx] = u;
}

// W_proj fp32 [128][V] -> bf16 chunk-interleaved: idx(n,k) = ((n>>4)*16 + (k>>3))*128 + (n&15)*8 + (k&7)
__global__ __launch_bounds__(256) void wpt2_kernel(const float* __restrict__ Wp,
                                                   unsigned short* __restrict__ W2){
  __shared__ unsigned short tile[64][136];
  int n0 = blockIdx.x * 64, tid = threadIdx.x;
  for (int idx = tid; idx < 8192; idx += 256){
    int k = idx >> 6, nn = idx & 63;
    int n = n0 + nn;
    float f = (n < Vv) ? Wp[(size_t)k * Vv + n] : 0.f;
    tile[nn][k] = f2bf(f);
  }
  __syncthreads();
  for (int idx = tid; idx < 1024; idx += 256){
    int c = idx >> 6, nn = idx & 63;          // c = k-chunk 0..15
    uint4 v = *reinterpret_cast<const uint4*>(&tile[nn][c * 8]);
    int n = n0 + nn;
    size_t dst = (((size_t)(n >> 4) * 16 + c) * 16 + (n & 15)) * 8;
    *reinterpret_cast<uint4*>(W2 + dst) = v;
  }
}

// ---------------- x-part precompute, packed-bf16 coalesced GEMV ----------------

__global__ __launch_bounds__(256) void pre2(
    const int* __restrict__ x, const int* __restrict__ y, const float* __restrict__ emb,
    const uint4* __restrict__ egx, const uint4* __restrict__ ecx,
    const float* __restrict__ egb, const float* __restrict__ ecb,
    const uint4* __restrict__ dgx, const uint4* __restrict__ dcx,
    const float* __restrict__ dgb, const float* __restrict__ dcb,
    float* __restrict__ epg, float* __restrict__ epc,
    float* __restrict__ dpg, float* __restrict__ dpc)
{
  __shared__ __align__(16) float er[304];
  int tid = threadIdx.x, ti = blockIdx.x, which = blockIdx.y;
  int tok = which ? y[ti] : x[ti];
  if (tid < 75)
    ((float4*)er)[tid] = ((const float4*)(emb + (size_t)tok * Ee))[tid];
  if (tid < 4) er[300 + tid] = 0.f;
  __syncthreads();
  const uint4* gx = which ? dgx : egx;
  const uint4* cx = which ? dcx : ecx;
  float g = (which ? dgb : egb)[tid] + dotP<38,256>(gx, tid, er);
  (which ? dpg : epg)[ti * 256 + tid] = g;
  if (tid < 128){
    float c = (which ? dcb : ecb)[tid] + dotP<38,128>(cx, tid, er);
    (which ? dpc : epc)[ti * 128 + tid] = c;
  }
}

// ---------------- recurrence: one block per batch, packed-bf16 coalesced weights ----------------

__global__ __launch_bounds__(256, 1) void recur3(
    const int* __restrict__ xlen,
    const float* __restrict__ epg, const float* __restrict__ epc,
    const float* __restrict__ dpg, const float* __restrict__ dpc,
    const uint4* __restrict__ e0g, const uint4* __restrict__ e0c,
    const uint4* __restrict__ e1g, const uint4* __restrict__ e1c,
    const float* __restrict__ e1_gb, const float* __restrict__ e1_cb,
    const uint4* __restrict__ d0g, const uint4* __restrict__ d0c,
    const uint4* __restrict__ d1g, const uint4* __restrict__ d1c,
    const float* __restrict__ d1_gb, const float* __restrict__ d1_cb,
    const uint4* __restrict__ wm, const uint4* __restrict__ wq,
    const uint4* __restrict__ wat, const float* __restrict__ v_att,
    unsigned short* __restrict__ na2)
{
  __shared__ __align__(16) float mem_s[Ss][Hh];
  __shared__ __align__(16) float keys_s[Ss][132];   // +4 pad
  __shared__ __align__(16) float h0[Hh];
  __shared__ __align__(16) float cat0[256], cat0c[256], cat1[256], cat1c[256], catA[256];
  __shared__ __align__(16) float gates[256];
  __shared__ __align__(16) float qv[Hh];
  __shared__ __align__(16) float vatt_s[Hh];
  __shared__ float part[Ss][8], als[Ss];

  const int tid = threadIdx.x, b = blockIdx.x;
  if (tid < 128){ h0[tid] = 0.f; cat1[128 + tid] = 0.f; vatt_s[tid] = v_att[tid]; }
  __syncthreads();
  const int xl = xlen[b];

  // ================= encoder =================
  for (int t = 0; t < Ss; t++){
    const int tix = b * Ss + t;
    {   // gates L0 + fused r*h (same thread owns r[k] and h0[k])
      float gs = sigm(epg[tix * 256 + tid] + dotP<16,256>(e0g, tid, h0));
      gates[tid] = gs;
      if (tid < 128) cat0c[tid] = gs * h0[tid];     // rh0
    }
    __syncthreads();
    if (tid < 128){   // cand L0
      float c = tanh_fast(epc[tix * 128 + tid] + dotP<16,128>(e0c, tid, cat0c));
      float u = gates[128 + tid];
      cat1[tid] = u * h0[tid] + (1.f - u) * c;      // n0 (unmasked, feeds L1)
    }
    __syncthreads();
    {   // gates L1 + fused r*h1
      float gs = sigm(e1_gb[tid] + dotP<32,256>(e1g, tid, cat1));
      gates[tid] = gs;
      if (tid < 128){ cat1c[tid] = cat1[tid]; cat1c[128 + tid] = gs * cat1[128 + tid]; }
    }
    __syncthreads();
    if (tid < 128){   // cand L1 + masked state update
      float c = tanh_fast(e1_cb[tid] + dotP<32,128>(e1c, tid, cat1c));
      float u = gates[128 + tid];
      float h1o = cat1[128 + tid];
      float nh = u * h1o + (1.f - u) * c;
      bool v = (t < xl);
      mem_s[t][tid] = v ? nh : 0.f;
      cat1[128 + tid] = v ? nh : h1o;
      h0[tid] = v ? cat1[tid] : h0[tid];
    }
    __syncthreads();
  }

  // keys = memory @ W_mem ; decoder state init
  for (int idx = tid; idx < Ss * Hh; idx += 256){
    int s = idx >> 7, j = idx & 127;
    keys_s[s][j] = dotP<16,128>(wm, j, mem_s[s]);
  }
  if (tid < 128){ cat0[tid] = 0.f; cat0[128 + tid] = h0[tid]; }
  __syncthreads();

  // ================= decoder =================
  for (int t = 0; t < Ss; t++){
    const int tix = b * Ss + t;
    {   // gates L0 (input [attn|h0]) + fused r*h0
      float gs = sigm(dpg[tix * 256 + tid] + dotP<32,256>(d0g, tid, cat0));
      gates[tid] = gs;
      if (tid < 128){ cat0c[tid] = cat0[tid]; cat0c[128 + tid] = gs * cat0[128 + tid]; }
    }
    __syncthreads();
    if (tid < 128){   // cand L0
      float c = tanh_fast(dpc[tix * 128 + tid] + dotP<32,128>(d0c, tid, cat0c));
      float u = gates[128 + tid];
      float nv = u * cat0[128 + tid] + (1.f - u) * c;
      cat1[tid] = nv; cat0[128 + tid] = nv;         // n0 / h0 (unconditional)
    }
    __syncthreads();
    {   // gates L1 + fused r*h1
      float gs = sigm(d1_gb[tid] + dotP<32,256>(d1g, tid, cat1));
      gates[tid] = gs;
      if (tid < 128){ cat1c[tid] = cat1[tid]; cat1c[128 + tid] = gs * cat1[128 + tid]; }
    }
    __syncthreads();
    if (tid < 128){   // cand L1
      float c = tanh_fast(d1_cb[tid] + dotP<32,128>(d1c, tid, cat1c));
      float u = gates[128 + tid];
      float h1o = cat1[128 + tid];
      float nh = u * h1o + (1.f - u) * c;
      catA[tid] = nh; cat1[128 + tid] = nh;         // n1 / h1
    }
    __syncthreads();
    if (tid < 128) qv[tid] = dotP<16,128>(wq, tid, catA);
    __syncthreads();
    if (tid < Ss * 8){   // score partials
      int s = tid >> 3, p = tid & 7;
      float a = 0.f;
#pragma unroll
      for (int c2 = 0; c2 < 16; c2++){
        int u2 = p * 16 + c2;
        a += tanh_fast(keys_s[s][u2] + qv[u2]) * vatt_s[u2];
      }
      part[s][p] = a;
    }
    __syncthreads();
    if (tid < 64){       // softmax over S in one wave
      int s = tid;
      bool valid = (s < Ss) && (s < xl);
      float sc = -3.4e38f;
      if (valid){ sc = 0.f;
#pragma unroll
        for (int p = 0; p < 8; p++) sc += part[s][p];
      }
      float mx = sc;
#pragma unroll
      for (int off = 32; off >= 1; off >>= 1) mx = fmaxf(mx, __shfl_xor(mx, off));
      float e = valid ? __expf(sc - mx) : 0.f;
      float sm = e;
#pragma unroll
      for (int off = 32; off >= 1; off >>= 1) sm += __shfl_xor(sm, off);
      if (s < Ss) als[s] = e / sm;
    }
    __syncthreads();
    if (tid < 128){      // context
      float a = 0.f;
#pragma unroll
      for (int s = 0; s < Ss; s++) a += als[s] * mem_s[s][tid];
      catA[128 + tid] = a;
    }
    __syncthreads();
    if (tid < 128){      // na = [n1,ctx] @ W_attn -> attn + chunk-interleaved bf16 output
      float a = dotP<32,128>(wat, tid, catA);
      cat0[tid] = a;
      na2[(((size_t)(tix >> 4) * 16 + (tid >> 3)) * 16 + (tix & 15)) * 8 + (tid & 7)] = f2bf(a);
    }
    __syncthreads();
  }
}

// ---------------- projection: MFMA 128x128 tiles, chunk-interleaved global fragments ----------------

__global__ __launch_bounds__(256) void proj3(
    const unsigned short* __restrict__ A2, const unsigned short* __restrict__ W2,
    const float* __restrict__ b_proj, const int* __restrict__ ylen,
    float* __restrict__ out)
{
  __shared__ int yl_s[Bb];
  const int tid = threadIdx.x;
  if (tid < Bb) yl_s[tid] = ylen[tid];
  __syncthreads();
  const int n0 = blockIdx.x * 128, m0 = blockIdx.y * 128;
  const int w = tid >> 6, lane = tid & 63, lm = lane & 15, qq = lane >> 4;
  const int wr = w >> 1, wc = w & 1;
  const int mtb = (m0 >> 4) + wr * 4, ntb = (n0 >> 4) + wc * 4;

  f32x4 acc[4][4];
#pragma unroll
  for (int mt = 0; mt < 4; mt++)
#pragma unroll
    for (int nt = 0; nt < 4; nt++) acc[mt][nt] = (f32x4){0.f,0.f,0.f,0.f};

#pragma unroll
  for (int ks = 0; ks < 4; ks++){
    int kc = ks * 4 + qq;
    bf16x8 bfr[4], afr[4];
#pragma unroll
    for (int nt = 0; nt < 4; nt++)
      bfr[nt] = *(const bf16x8*)(W2 + (((size_t)(ntb + nt) * 16 + kc) * 16 + lm) * 8);
#pragma unroll
    for (int mt = 0; mt < 4; mt++)
      afr[mt] = *(const bf16x8*)(A2 + (((size_t)(mtb + mt) * 16 + kc) * 16 + lm) * 8);
#pragma unroll
    for (int mt = 0; mt < 4; mt++)
#pragma unroll
      for (int nt = 0; nt < 4; nt++)
        acc[mt][nt] = __builtin_amdgcn_mfma_f32_16x16x32_bf16(afr[mt], bfr[nt], acc[mt][nt], 0, 0, 0);
  }

  float bp[4];
#pragma unroll
  for (int nt = 0; nt < 4; nt++){
    int col = n0 + wc * 64 + nt * 16 + lm;
    bp[nt] = (col < Vv) ? b_proj[col] : 0.f;
  }

  // C/D: col = lane&15, row = (lane>>4)*4 + reg
#pragma unroll
  for (int mt = 0; mt < 4; mt++){
    int rowb = m0 + wr * 64 + mt * 16 + qq * 4;
#pragma unroll
    for (int r = 0; r < 4; r++){
      int rr = rowb + r;
      int bb = rr / Ss, tt = rr - bb * Ss;
      bool vr = tt < yl_s[bb];
#pragma unroll
      for (int nt = 0; nt < 4; nt++){
        int col = n0 + wc * 64 + nt * 16 + lm;
        if (col < Vv)
          out[(size_t)rr * Vv + col] = vr ? (acc[mt][nt][r] + bp[nt]) : 0.f;
      }
    }
  }
}

extern "C" void kernel_launch(void* const* d_in, const int* in_sizes, int n_in,
                              void* d_out, int out_size, void* d_ws, size_t ws_size,
                              hipStream_t stream) {
  const int*   x        = (const int*)d_in[0];
  const int*   x_length = (const int*)d_in[1];
  const int*   y        = (const int*)d_in[2];
  const int*   y_length = (const int*)d_in[3];
  const float* emb      = (const float*)d_in[4];
  const float* e0_gk = (const float*)d_in[5];  const float* e0_gb = (const float*)d_in[6];
  const float* e0_ck = (const float*)d_in[7];  const float* e0_cb = (const float*)d_in[8];
  const float* e1_gk = (const float*)d_in[9];  const float* e1_gb = (const float*)d_in[10];
  const float* e1_ck = (const float*)d_in[11]; const float* e1_cb = (const float*)d_in[12];
  const float* d0_gk = (const float*)d_in[13]; const float* d0_gb = (const float*)d_in[14];
  const float* d0_ck = (const float*)d_in[15]; const float* d0_cb = (const float*)d_in[16];
  const float* d1_gk = (const float*)d_in[17]; const float* d1_gb = (const float*)d_in[18];
  const float* d1_ck = (const float*)d_in[19]; const float* d1_cb = (const float*)d_in[20];
  const float* W_mem = (const float*)d_in[21]; const float* W_q   = (const float*)d_in[22];
  const float* v_att = (const float*)d_in[23]; const float* W_attn= (const float*)d_in[24];
  const float* W_proj= (const float*)d_in[25]; const float* b_proj= (const float*)d_in[26];
  float* out = (float*)d_out;

  size_t off = 0;
  auto alloc = [&](size_t bytes) -> void* {
    void* p = (char*)d_ws + off;
    off += (bytes + 255) & ~(size_t)255;
    return p;
  };
  unsigned short* W2  = (unsigned short*)alloc((size_t)Vpad * 128 * 2);
  unsigned short* na2 = (unsigned short*)alloc((size_t)Bb * Ss * Hh * 2);
  float* epg = (float*)alloc((size_t)Bb*Ss*256*4);
  float* epc = (float*)alloc((size_t)Bb*Ss*128*4);
  float* dpg = (float*)alloc((size_t)Bb*Ss*256*4);
  float* dpc = (float*)alloc((size_t)Bb*Ss*128*4);
  uint4* e0g  = (uint4*)alloc(16*256*16);
  uint4* e0c  = (uint4*)alloc(16*128*16);
  uint4* e1g  = (uint4*)alloc(32*256*16);
  uint4* e1c  = (uint4*)alloc(32*128*16);
  uint4* d0g  = (uint4*)alloc(32*256*16);
  uint4* d0c  = (uint4*)alloc(32*128*16);
  uint4* d1g  = (uint4*)alloc(32*256*16);
  uint4* d1c  = (uint4*)alloc(32*128*16);
  uint4* wm   = (uint4*)alloc(16*128*16);
  uint4* wq   = (uint4*)alloc(16*128*16);
  uint4* wat  = (uint4*)alloc(32*128*16);
  uint4* e0gx = (uint4*)alloc(38*256*16);
  uint4* e0cx = (uint4*)alloc(38*128*16);
  uint4* d0gx = (uint4*)alloc(38*256*16);
  uint4* d0cx = (uint4*)alloc(38*128*16);

  PL L;
  L.m[0]  = { e0_gk, e0g,  300, 128, 256 };
  L.m[1]  = { e0_ck, e0c,  300, 128, 128 };
  L.m[2]  = { e1_gk, e1g,    0, 256, 256 };
  L.m[3]  = { e1_ck, e1c,    0, 256, 128 };
  L.m[4]  = { d0_gk, d0g,  300, 256, 256 };
  L.m[5]  = { d0_ck, d0c,  300, 256, 128 };
  L.m[6]  = { d1_gk, d1g,    0, 256, 256 };
  L.m[7]  = { d1_ck, d1c,    0, 256, 128 };
  L.m[8]  = { W_mem, wm,     0, 128, 128 };
  L.m[9]  = { W_q,   wq,     0, 128, 128 };
  L.m[10] = { W_attn,wat,    0, 256, 128 };
  L.m[11] = { e0_gk, e0gx,   0, 300, 256 };
  L.m[12] = { e0_ck, e0cx,   0, 300, 128 };
  L.m[13] = { d0_gk, d0gx,   0, 300, 256 };
  L.m[14] = { d0_ck, d0cx,   0, 300, 128 };

  pack_kernel<<<dim3(38, 15), 256, 0, stream>>>(L);
  wpt2_kernel<<<Vpad / 64, 256, 0, stream>>>(W_proj, W2);
  pre2<<<dim3(Bb * Ss, 2), 256, 0, stream>>>(
      x, y, emb, e0gx, e0cx, e0_gb, e0_cb,
      d0gx, d0cx, d0_gb, d0_cb, epg, epc, dpg, dpc);
  recur3<<<Bb, 256, 0, stream>>>(
      x_length, epg, epc, dpg, dpc,
      e0g, e0c, e1g, e1c, e1_gb, e1_cb,
      d0g, d0c, d1g, d1c, d1_gb, d1_cb,
      wm, wq, wat, v_att, na2);
  proj3<<<dim3(Vpad / 128, (Bb * Ss) / 128), 256, 0, stream>>>(
      na2, W2, b_proj, y_length, out);
}